// Round 1
// baseline (597.120 us; speedup 1.0000x reference)
//
#include <hip/hip_runtime.h>

// Noisy LIF neuron: u = 0.5*u + x_t - 0.5*noise_t; o = (u > 1); u = o ? 0 : u.
// Shapes: x, noise, out all [B=16, T=64, N=65536] fp32, N innermost.
// Scan is sequential in T only; one thread owns 4 consecutive n lanes.

constexpr int B = 16;
constexpr int T = 64;
constexpr int N = 65536;
constexpr int N4 = N / 4;          // float4 columns per (b,t) row
constexpr int BN4 = B * N4;        // total threads

__global__ __launch_bounds__(256) void lif_kernel(
    const float4* __restrict__ x,
    const float4* __restrict__ noise,
    float4* __restrict__ out)
{
    int idx = blockIdx.x * blockDim.x + threadIdx.x;   // [0, BN4)
    if (idx >= BN4) return;
    int b  = idx / N4;
    int n4 = idx - b * N4;

    // element index into [B, T, N4] float4 array; fits in int32 (max ~16.7M)
    int base = b * (T * N4) + n4;

    float ux = 0.f, uy = 0.f, uz = 0.f, uw = 0.f;

#pragma unroll 4
    for (int t = 0; t < T; ++t) {
        float4 xt = x[base];
        float4 nt = noise[base];

        // 0.5f multiplies are exact (power of two), so fma contraction is
        // bit-identical to numpy's separately-rounded ops.
        ux = 0.5f * ux + xt.x - 0.5f * nt.x;
        uy = 0.5f * uy + xt.y - 0.5f * nt.y;
        uz = 0.5f * uz + xt.z - 0.5f * nt.z;
        uw = 0.5f * uw + xt.w - 0.5f * nt.w;

        float4 o;
        o.x = (ux > 1.0f) ? 1.0f : 0.0f;
        o.y = (uy > 1.0f) ? 1.0f : 0.0f;
        o.z = (uz > 1.0f) ? 1.0f : 0.0f;
        o.w = (uw > 1.0f) ? 1.0f : 0.0f;

        // hard reset on spike
        ux = (o.x != 0.0f) ? 0.0f : ux;
        uy = (o.y != 0.0f) ? 0.0f : uy;
        uz = (o.z != 0.0f) ? 0.0f : uz;
        uw = (o.w != 0.0f) ? 0.0f : uw;

        out[base] = o;
        base += N4;
    }
}

extern "C" void kernel_launch(void* const* d_in, const int* in_sizes, int n_in,
                              void* d_out, int out_size, void* d_ws, size_t ws_size,
                              hipStream_t stream) {
    const float4* x     = (const float4*)d_in[0];
    const float4* noise = (const float4*)d_in[1];
    float4* out         = (float4*)d_out;

    dim3 block(256);
    dim3 grid(BN4 / 256);   // 262144 / 256 = 1024 blocks
    lif_kernel<<<grid, block, 0, stream>>>(x, noise, out);
}

// Round 3
// 592.563 us; speedup vs baseline: 1.0077x; 1.0077x over previous
//
#include <hip/hip_runtime.h>

// Noisy LIF neuron: u = 0.5*u + x_t - 0.5*noise_t; o = (u > 1); u = o ? 0 : u.
// Shapes: x, noise, out all [B=16, T=64, N=65536] fp32, N innermost.
// Scan is sequential in T only; one thread owns 2 consecutive n lanes.
//
// R1 analysis: float4/thread gave only 16 waves/CU (occ 34%), 2.6 TB/s,
// latency-bound. float2/thread doubles wave count to 32/CU (100% static
// occupancy) while keeping loads fully coalesced (512 B per wave-instr).
//
// Use a clang native vector type: __builtin_nontemporal_store rejects the
// HIP_vector_type<float,2> class (R2 compile error).

typedef float v2f __attribute__((ext_vector_type(2)));

constexpr int B = 16;
constexpr int T = 64;
constexpr int N = 65536;
constexpr int N2 = N / 2;          // float2 columns per (b,t) row = 32768
constexpr int BN2 = B * N2;        // total threads = 524288

__global__ __launch_bounds__(256) void lif_kernel(
    const v2f* __restrict__ x,
    const v2f* __restrict__ noise,
    v2f* __restrict__ out)
{
    int idx = blockIdx.x * blockDim.x + threadIdx.x;   // [0, BN2)
    int b  = idx >> 15;            // idx / N2
    int n2 = idx & (N2 - 1);       // idx % N2

    // element index into [B, T, N2] v2f array; fits easily in int32
    int base = b * (T * N2) + n2;

    float ux = 0.f, uy = 0.f;

#pragma unroll 8
    for (int t = 0; t < T; ++t) {
        v2f xt = x[base];
        v2f nt = noise[base];

        // 0.5f multiplies are exact (power of two), so fma contraction is
        // bit-identical to numpy's separately-rounded ops.
        ux = 0.5f * ux + xt.x - 0.5f * nt.x;
        uy = 0.5f * uy + xt.y - 0.5f * nt.y;

        v2f o;
        o.x = (ux > 1.0f) ? 1.0f : 0.0f;
        o.y = (uy > 1.0f) ? 1.0f : 0.0f;

        // hard reset on spike
        ux = (o.x != 0.0f) ? 0.0f : ux;
        uy = (o.y != 0.0f) ? 0.0f : uy;

        // nontemporal store: output is never re-read; don't evict the
        // L3-warm inputs (harness restore leaves them resident).
        __builtin_nontemporal_store(o, &out[base]);

        base += N2;
    }
}

extern "C" void kernel_launch(void* const* d_in, const int* in_sizes, int n_in,
                              void* d_out, int out_size, void* d_ws, size_t ws_size,
                              hipStream_t stream) {
    const v2f* x     = (const v2f*)d_in[0];
    const v2f* noise = (const v2f*)d_in[1];
    v2f* out         = (v2f*)d_out;

    dim3 block(256);
    dim3 grid(BN2 / 256);   // 524288 / 256 = 2048 blocks
    lif_kernel<<<grid, block, 0, stream>>>(x, noise, out);
}

// Round 4
// 590.238 us; speedup vs baseline: 1.0117x; 1.0039x over previous
//
#include <hip/hip_runtime.h>

// Noisy LIF neuron: u = 0.5*u + x_t - 0.5*noise_t; o = (u > 1); u = o ? 0 : u.
// Shapes: x, noise, out all [B=16, T=64, N=65536] fp32, N innermost.
//
// R3 post-mortem: occupancy 34->63% changed nothing (2.5 TB/s both) and the
// compiler allocated only 32 VGPRs -- it rolled the unroll back to ~2 loads
// in flight per wave. This round: explicit depth-8 circular prefetch with the
// T-loop fully unrolled so buffer slots are static registers -> 16 loads
// outstanding per wave, fine-grained vmcnt waits.

typedef float v2f __attribute__((ext_vector_type(2)));

constexpr int B = 16;
constexpr int T = 64;
constexpr int N = 65536;
constexpr int N2 = N / 2;          // v2f columns per (b,t) row = 32768
constexpr int BN2 = B * N2;        // total threads = 524288
constexpr int D = 8;               // prefetch depth (iterations ahead)

__global__ __launch_bounds__(256, 4) void lif_kernel(
    const v2f* __restrict__ x,
    const v2f* __restrict__ noise,
    v2f* __restrict__ out)
{
    int idx = blockIdx.x * blockDim.x + threadIdx.x;   // [0, BN2)
    int b  = idx >> 15;            // idx / N2
    int n2 = idx & (N2 - 1);       // idx % N2

    int base = b * (T * N2) + n2;  // index into [B, T, N2] v2f array

    v2f xb[D], nb[D];

    // Prime the pipeline: 2*D = 16 loads issued back-to-back, no waits.
#pragma unroll
    for (int d = 0; d < D; ++d) {
        xb[d] = x[base + d * N2];
        nb[d] = noise[base + d * N2];
    }

    float ux = 0.f, uy = 0.f;

#pragma unroll
    for (int t = 0; t < T; ++t) {
        const int slot = t % D;    // static after full unroll
        v2f xt = xb[slot];
        v2f nt = nb[slot];

        // Refill the slot D iterations ahead (static guard after unroll).
        if (t + D < T) {
            xb[slot] = x[base + (t + D) * N2];
            nb[slot] = noise[base + (t + D) * N2];
        }

        // 0.5f multiplies are exact (power of two), so fma contraction is
        // bit-identical to numpy's separately-rounded ops.
        ux = 0.5f * ux + xt.x - 0.5f * nt.x;
        uy = 0.5f * uy + xt.y - 0.5f * nt.y;

        v2f o;
        o.x = (ux > 1.0f) ? 1.0f : 0.0f;
        o.y = (uy > 1.0f) ? 1.0f : 0.0f;

        ux = (o.x != 0.0f) ? 0.0f : ux;
        uy = (o.y != 0.0f) ? 0.0f : uy;

        // nontemporal store: output is never re-read.
        __builtin_nontemporal_store(o, &out[base + t * N2]);
    }
}

extern "C" void kernel_launch(void* const* d_in, const int* in_sizes, int n_in,
                              void* d_out, int out_size, void* d_ws, size_t ws_size,
                              hipStream_t stream) {
    const v2f* x     = (const v2f*)d_in[0];
    const v2f* noise = (const v2f*)d_in[1];
    v2f* out         = (v2f*)d_out;

    dim3 block(256);
    dim3 grid(BN2 / 256);   // 524288 / 256 = 2048 blocks
    lif_kernel<<<grid, block, 0, stream>>>(x, noise, out);
}